// Round 5
// baseline (239.250 us; speedup 1.0000x reference)
//
#include <hip/hip_runtime.h>
#include <math.h>

#define BB 16
#define MM 2048
#define SS 6
#define EE 128
#define LCC 512
#define VV 32000

typedef __attribute__((ext_vector_type(8))) __bf16 bf16x8;
typedef __attribute__((ext_vector_type(4))) float f32x4;

#define XS_STRIDE 264   // 256+8 bf16 pad
#define HS_STRIDE 136   // 128+8 bf16 pad

// ---------------------------------------------------------------------------
// megaprep: fp32->bf16 of C[0..3), dh, tf; weight transpose-convert.
// ---------------------------------------------------------------------------
static __device__ inline void cvt8(const float* __restrict__ src, __bf16* __restrict__ dst) {
    const float4 a = *(const float4*)src;
    const float4 b = *(const float4*)(src + 4);
    bf16x8 o;
    o[0] = (__bf16)a.x; o[1] = (__bf16)a.y; o[2] = (__bf16)a.z; o[3] = (__bf16)a.w;
    o[4] = (__bf16)b.x; o[5] = (__bf16)b.y; o[6] = (__bf16)b.z; o[7] = (__bf16)b.w;
    *(bf16x8*)dst = o;
}

#define N_C8  (3 * VV * EE / 8)        // 1,536,000
#define N_D8  (BB * LCC * EE / 8)      // 131,072
#define N_T8  (BB * EE / 8)            // 256
#define N_W1  (256 * 128)              // 32,768
#define N_W2  (128 * 128)              // 16,384
#define N_PREP (N_C8 + N_D8 + N_T8 + N_W1 + N_W2)   // 1,716,480 = 6705*256

__global__ __launch_bounds__(256)
void megaprep(const float* __restrict__ C, const float* __restrict__ dh,
              const float* __restrict__ tf, const float* __restrict__ W1,
              const float* __restrict__ W2,
              __bf16* __restrict__ Cb, __bf16* __restrict__ dhb,
              __bf16* __restrict__ tfb, __bf16* __restrict__ w1t,
              __bf16* __restrict__ w2t)
{
    int i = blockIdx.x * 256 + threadIdx.x;
    if (i < N_C8) { cvt8(C + (size_t)i * 8, Cb + (size_t)i * 8); return; }
    i -= N_C8;
    if (i < N_D8) { cvt8(dh + (size_t)i * 8, dhb + (size_t)i * 8); return; }
    i -= N_D8;
    if (i < N_T8) { cvt8(tf + i * 8, tfb + i * 8); return; }
    i -= N_T8;
    if (i < N_W1) { const int n = i >> 8, k = i & 255; w1t[i] = (__bf16)W1[k * EE + n]; return; }
    i -= N_W1;
    if (i < N_W2) { const int n = i >> 7, k = i & 127; w2t[i] = (__bf16)W2[k * EE + n]; }
}

// ---------------------------------------------------------------------------
// Fused embed gather-sum + add_lm + MFMA MLP, 3 hops in one grid.
// hop 0: logits0 computed in-register, m0 never stored. hops 1,2: Y -> mout.
// LDS: Hs ALIASES Xs (Xs dead before Hs written) -> 17.7 KB -> 8 blocks/CU.
// ---------------------------------------------------------------------------
__global__ __launch_bounds__(256, 8)
void embed_mlp_mfma(const int* __restrict__ story,
                    const int* __restrict__ kb_len,
                    const int* __restrict__ conv_len,
                    const __bf16* __restrict__ Cb,
                    const __bf16* __restrict__ dhb,
                    const __bf16* __restrict__ tfb,
                    const __bf16* __restrict__ w1t, const float* __restrict__ b1,
                    const __bf16* __restrict__ w2t, const float* __restrict__ b2,
                    const float* __restrict__ gp, const float* __restrict__ query,
                    __bf16* __restrict__ mout, float* __restrict__ lbuf0)
{
    __shared__ __bf16 Xs[32 * XS_STRIDE];   // 16,896 B; Hs aliases (needs 8,704 B)
    __shared__ int    sidx[32 * SS];
    __bf16* Hs   = Xs;
    float*  plog = (float*)Xs;

    const int bid  = blockIdx.x;
    const int hop  = bid >> 10;
    const int row0 = (bid & 1023) * 32;
    const int b    = row0 >> 11;
    const int tid  = threadIdx.x;

    const __bf16* Ck = Cb + (size_t)hop * VV * EE;

    for (int i = tid; i < 32 * SS; i += 256) sidx[i] = story[(size_t)row0 * SS + i];

    const int kb   = kb_len[b];
    const int cl   = conv_len[b];
    const int rgrp = tid >> 4;
    const int e8   = (tid & 15) * 8;
    const bf16x8 tf8 = *(const bf16x8*)&tfb[b * EE + e8];
    __syncthreads();

    // ---- gather: 2 passes x 16 rows, all loads issued before use ----
    bf16x8 g[2][SS], dv[2];
    #pragma unroll
    for (int p = 0; p < 2; ++p) {
        const int r = p * 16 + rgrp;
        const int* si = &sidx[r * SS];
        #pragma unroll
        for (int s = 0; s < SS; ++s)
            g[p][s] = *(const bf16x8*)&Ck[(size_t)si[s] * EE + e8];
        const int j = ((row0 + r) & (MM - 1)) - kb;
        if (j >= 0 && j < cl) {
            dv[p] = *(const bf16x8*)&dhb[((size_t)b * LCC + j) * EE + e8];
        } else {
            bf16x8 z;
            #pragma unroll
            for (int q = 0; q < 8; ++q) z[q] = (__bf16)0.f;
            dv[p] = z;
        }
    }
    #pragma unroll
    for (int p = 0; p < 2; ++p) {
        const int r = p * 16 + rgrp;
        bf16x8 pk;
        #pragma unroll
        for (int q = 0; q < 8; ++q) {
            float s = (float)dv[p][q];
            #pragma unroll
            for (int s6 = 0; s6 < SS; ++s6) s += (float)g[p][s6][q];
            pk[q] = (__bf16)s;
        }
        *(bf16x8*)&Xs[r * XS_STRIDE + e8]      = pk;
        *(bf16x8*)&Xs[r * XS_STRIDE + EE + e8] = tf8;
    }
    __syncthreads();

    const int w       = tid >> 6;
    const int lane    = tid & 63;
    const int lr      = lane & 15;
    const int lk      = lane >> 4;
    const int colbase = w * 32;

    // ---- GEMM1: H = lrelu(X @ W1 + b1) ----
    f32x4 acc1[2][2];
    #pragma unroll
    for (int i = 0; i < 2; ++i)
        #pragma unroll
        for (int j = 0; j < 2; ++j) acc1[i][j] = (f32x4){0.f, 0.f, 0.f, 0.f};

    for (int ks = 0; ks < 8; ++ks) {
        bf16x8 a[2], bw[2];
        #pragma unroll
        for (int mt = 0; mt < 2; ++mt)
            a[mt] = *(const bf16x8*)&Xs[(mt * 16 + lr) * XS_STRIDE + ks * 32 + lk * 8];
        #pragma unroll
        for (int nt = 0; nt < 2; ++nt)
            bw[nt] = *(const bf16x8*)&w1t[(size_t)(colbase + nt * 16 + lr) * 256 + ks * 32 + lk * 8];
        #pragma unroll
        for (int mt = 0; mt < 2; ++mt)
            #pragma unroll
            for (int nt = 0; nt < 2; ++nt)
                acc1[mt][nt] = __builtin_amdgcn_mfma_f32_16x16x32_bf16(a[mt], bw[nt], acc1[mt][nt], 0, 0, 0);
    }
    __syncthreads();   // all Xs reads complete before Hs (alias) is written
    {
        const float b1v[2] = { b1[colbase + lr], b1[colbase + 16 + lr] };
        #pragma unroll
        for (int mt = 0; mt < 2; ++mt)
            #pragma unroll
            for (int nt = 0; nt < 2; ++nt)
                #pragma unroll
                for (int reg = 0; reg < 4; ++reg) {
                    float h = acc1[mt][nt][reg] + b1v[nt];
                    h = (h > 0.f) ? h : 0.1f * h;
                    Hs[(mt * 16 + lk * 4 + reg) * HS_STRIDE + colbase + nt * 16 + lr] = (__bf16)h;
                }
    }
    __syncthreads();

    // ---- GEMM2: Y = H @ W2 + b2 ----
    f32x4 acc2[2][2];
    #pragma unroll
    for (int i = 0; i < 2; ++i)
        #pragma unroll
        for (int j = 0; j < 2; ++j) acc2[i][j] = (f32x4){0.f, 0.f, 0.f, 0.f};

    for (int ks = 0; ks < 4; ++ks) {
        bf16x8 a[2], bw[2];
        #pragma unroll
        for (int mt = 0; mt < 2; ++mt)
            a[mt] = *(const bf16x8*)&Hs[(mt * 16 + lr) * HS_STRIDE + ks * 32 + lk * 8];
        #pragma unroll
        for (int nt = 0; nt < 2; ++nt)
            bw[nt] = *(const bf16x8*)&w2t[(size_t)(colbase + nt * 16 + lr) * 128 + ks * 32 + lk * 8];
        #pragma unroll
        for (int mt = 0; mt < 2; ++mt)
            #pragma unroll
            for (int nt = 0; nt < 2; ++nt)
                acc2[mt][nt] = __builtin_amdgcn_mfma_f32_16x16x32_bf16(a[mt], bw[nt], acc2[mt][nt], 0, 0, 0);
    }

    const float b2v[2] = { b2[colbase + lr], b2[colbase + 16 + lr] };

    if (hop == 0) {
        const float qv0 = query[b * EE + colbase + lr];
        const float qv1 = query[b * EE + colbase + 16 + lr];
        __syncthreads();    // Hs reads done; reuse as plog
        #pragma unroll
        for (int mt = 0; mt < 2; ++mt)
            #pragma unroll
            for (int reg = 0; reg < 4; ++reg) {
                float p = (acc2[mt][0][reg] + b2v[0]) * qv0
                        + (acc2[mt][1][reg] + b2v[1]) * qv1;
                p += __shfl_xor(p, 1, 64);
                p += __shfl_xor(p, 2, 64);
                p += __shfl_xor(p, 4, 64);
                p += __shfl_xor(p, 8, 64);
                if (lr == 0) plog[(mt * 16 + lk * 4 + reg) * 4 + w] = p;
            }
        __syncthreads();
        if (tid < 32) {
            const float l = plog[tid * 4] + plog[tid * 4 + 1] + plog[tid * 4 + 2] + plog[tid * 4 + 3];
            lbuf0[row0 + tid] = l * gp[row0 + tid];
        }
    } else {
        __bf16* out = mout + (size_t)(hop - 1) * 32768 * EE;
        #pragma unroll
        for (int mt = 0; mt < 2; ++mt)
            #pragma unroll
            for (int nt = 0; nt < 2; ++nt)
                #pragma unroll
                for (int reg = 0; reg < 4; ++reg) {
                    const int rg_ = row0 + mt * 16 + lk * 4 + reg;
                    out[(size_t)rg_ * EE + colbase + nt * 16 + lr] =
                        (__bf16)(acc2[mt][nt][reg] + b2v[nt]);
                }
    }
}

// ---------------------------------------------------------------------------
// tail: whole 3-hop attention per batch row. 16 blocks x 1024 thr (16 waves).
// loop hop=0..2: softmax(lls) [hop2: -> out_soft, done];
//                wls = gp*soft; uq += mh^T wls; lls = gp*(mh uq)
//                (hop1's logits are logits2 -> out_logits).
// ---------------------------------------------------------------------------
__global__ __launch_bounds__(1024)
void tail_kernel(const __bf16* __restrict__ m, const float* __restrict__ gp,
                 const float* __restrict__ lbuf0, const float* __restrict__ query,
                 float* __restrict__ out_logits, float* __restrict__ out_soft)
{
    __shared__ float uqs[128];
    __shared__ float wls[2048];
    __shared__ float lls[2048];
    __shared__ float part[16][128];
    __shared__ float redm[16], reds[16];

    const int b    = blockIdx.x;
    const int tid  = threadIdx.x;
    const int w    = tid >> 6;
    const int lane = tid & 63;
    const int g    = lane >> 4;
    const int l16  = lane & 15;
    const float* gpb = gp + (size_t)b * MM;

    if (tid < 128) uqs[tid] = query[b * EE + tid];
    lls[tid]        = lbuf0[(size_t)b * MM + tid];
    lls[tid + 1024] = lbuf0[(size_t)b * MM + tid + 1024];
    __syncthreads();

    for (int hop = 0; hop < 3; ++hop) {
        // ---- block softmax over lls ----
        const float v0 = lls[tid], v1 = lls[tid + 1024];
        float mx = fmaxf(v0, v1);
        #pragma unroll
        for (int off = 32; off > 0; off >>= 1) mx = fmaxf(mx, __shfl_xor(mx, off, 64));
        if (lane == 0) redm[w] = mx;
        __syncthreads();
        float bmx = redm[0];
        #pragma unroll
        for (int i = 1; i < 16; ++i) bmx = fmaxf(bmx, redm[i]);
        const float e0 = __expf(v0 - bmx), e1 = __expf(v1 - bmx);
        float sm = e0 + e1;
        #pragma unroll
        for (int off = 32; off > 0; off >>= 1) sm += __shfl_xor(sm, off, 64);
        if (lane == 0) reds[w] = sm;
        __syncthreads();
        float bs = 0.f;
        #pragma unroll
        for (int i = 0; i < 16; ++i) bs += reds[i];
        const float inv = 1.f / bs;

        if (hop == 2) {
            out_soft[(size_t)b * MM + tid]        = e0 * inv;
            out_soft[(size_t)b * MM + tid + 1024] = e1 * inv;
            return;
        }
        wls[tid]        = e0 * inv * gpb[tid];
        wls[tid + 1024] = e1 * inv * gpb[tid + 1024];
        __syncthreads();

        const __bf16* mh = m + ((size_t)hop * 32768 + (size_t)b * MM) * EE;

        // ---- update: uq += sum_row wls[row] * mh[row,:] (wave w: 128 rows) ----
        float acc[8];
        #pragma unroll
        for (int q = 0; q < 8; ++q) acc[q] = 0.f;
        for (int it = 0; it < 32; ++it) {
            const int row = w * 128 + it * 4 + g;
            const bf16x8 mv = *(const bf16x8*)&mh[(size_t)row * EE + l16 * 8];
            const float wg = wls[row];
            #pragma unroll
            for (int q = 0; q < 8; ++q) acc[q] += wg * (float)mv[q];
        }
        #pragma unroll
        for (int q = 0; q < 8; ++q) {
            acc[q] += __shfl_xor(acc[q], 16, 64);
            acc[q] += __shfl_xor(acc[q], 32, 64);
        }
        if (lane < 16) {
            #pragma unroll
            for (int q = 0; q < 8; ++q) part[w][l16 * 8 + q] = acc[q];
        }
        __syncthreads();
        if (tid < 128) {
            float s = uqs[tid];
            #pragma unroll
            for (int ww = 0; ww < 16; ++ww) s += part[ww][tid];
            uqs[tid] = s;
        }
        __syncthreads();

        // ---- logits: lls[row] = gp * dot(mh[row,:], uq) ----
        float u[8];
        #pragma unroll
        for (int j = 0; j < 8; ++j) u[j] = uqs[l16 * 8 + j];
        for (int it = 0; it < 32; ++it) {
            const int row = w * 128 + it * 4 + g;
            const bf16x8 mv = *(const bf16x8*)&mh[(size_t)row * EE + l16 * 8];
            float p = 0.f;
            #pragma unroll
            for (int j = 0; j < 8; ++j) p += (float)mv[j] * u[j];
            p += __shfl_xor(p, 1, 64);
            p += __shfl_xor(p, 2, 64);
            p += __shfl_xor(p, 4, 64);
            p += __shfl_xor(p, 8, 64);
            if (l16 == 0) {
                const float lv = p * gpb[row];
                lls[row] = lv;
                if (hop == 1) out_logits[(size_t)b * MM + row] = lv;
            }
        }
        __syncthreads();
    }
}

// ---------------------------------------------------------------------------
extern "C" void kernel_launch(void* const* d_in, const int* in_sizes, int n_in,
                              void* d_out, int out_size, void* d_ws, size_t ws_size,
                              hipStream_t stream) {
    const int*   story    = (const int*)d_in[0];
    const int*   kb_len   = (const int*)d_in[1];
    const int*   conv_len = (const int*)d_in[2];
    // d_in[3] = hidden (dead w.r.t. outputs)
    const float* dh       = (const float*)d_in[4];
    const float* tf       = (const float*)d_in[5];
    const float* query    = (const float*)d_in[6];
    const float* gp       = (const float*)d_in[7];
    const float* C        = (const float*)d_in[8];
    const float* wA1      = (const float*)d_in[9];
    const float* bA1      = (const float*)d_in[10];
    const float* wA2      = (const float*)d_in[11];
    const float* bA2      = (const float*)d_in[12];
    // wC1/bC1/wC2/bC2, wf/bf: dead w.r.t. outputs

    char* ws = (char*)d_ws;
    const size_t M_ELEMS = (size_t)32768 * EE;
    size_t off = 0;
    __bf16* m   = (__bf16*)(ws + off); off += 2 * M_ELEMS * sizeof(__bf16);        // m1, m2
    __bf16* Cb  = (__bf16*)(ws + off); off += (size_t)3 * VV * EE * sizeof(__bf16);
    __bf16* dhb = (__bf16*)(ws + off); off += (size_t)BB * LCC * EE * sizeof(__bf16);
    __bf16* tfb = (__bf16*)(ws + off); off += (size_t)BB * EE * sizeof(__bf16);
    __bf16* w1t = (__bf16*)(ws + off); off += 256 * 128 * sizeof(__bf16);
    __bf16* w2t = (__bf16*)(ws + off); off += 128 * 128 * sizeof(__bf16);
    float* lbuf = (float*)(ws + off);  off += (size_t)BB * MM * sizeof(float);

    float* out_soft   = (float*)d_out;
    float* out_logits = out_soft + (size_t)BB * MM;

    megaprep<<<N_PREP / 256, 256, 0, stream>>>(C, dh, tf, wA1, wA2,
                                               Cb, dhb, tfb, w1t, w2t);
    embed_mlp_mfma<<<3072, 256, 0, stream>>>(story, kb_len, conv_len, Cb, dhb, tfb,
                                             w1t, bA1, w2t, bA2, gp, query, m, lbuf);
    tail_kernel<<<BB, 1024, 0, stream>>>(m, gp, lbuf, query, out_logits, out_soft);
}